// Round 2
// baseline (184.163 us; speedup 1.0000x reference)
//
#include <hip/hip_runtime.h>

#define NPTS 65536
#define CCH  32
#define DDIM 64
#define GVOX (DDIM*DDIM*DDIM)   // B=1 -> 262144 voxels
#define MAXTILES 4128           // >= 65536/16 + 27 (per-class padding)
#define NSLOTCAP (MAXTILES*16)  // zero-row sentinel index
#define NCELL 512               // 8x8x8 coarse cells
#define KEYS (27*NCELL)         // 13824 (class, cell) keys
#define CHUNK (KEYS/256)        // 54

typedef _Float16 half8  __attribute__((ext_vector_type(8)));
typedef float    floatx4 __attribute__((ext_vector_type(4)));

// ---------------- prep0: init (one launch) ----------------
// ranges: map init | sorted init | pcoords init | weight transpose | sentinel rows | counters
__global__ __launch_bounds__(256) void k_prep0(
    int* __restrict__ map, int* __restrict__ sorted, int* __restrict__ pcoords,
    const float* __restrict__ k1, const float* __restrict__ k2,
    _Float16* __restrict__ w1, _Float16* __restrict__ w2,
    _Float16* __restrict__ valsh, _Float16* __restrict__ hh,
    int* __restrict__ cntslot)             // [cnt | slot], 2*KEYS ints
{
  int tid = blockIdx.x * 256 + threadIdx.x;
  if (tid < GVOX/4) { ((int4*)map)[tid] = make_int4(-1,-1,-1,-1); return; }
  tid -= GVOX/4;
  if (tid < MAXTILES*4) { ((int4*)sorted)[tid] = make_int4(NPTS,NPTS,NPTS,NPTS); return; }
  tid -= MAXTILES*4;
  if (tid < MAXTILES*4) { ((int4*)pcoords)[tid] = make_int4(0,0,0,0); return; }
  tid -= MAXTILES*4;
  if (tid < 27*CCH*CCH) {                  // (t,cin,cout) f32 -> (t,cout,cin) f16
    int t = tid/(CCH*CCH), r = tid%(CCH*CCH);
    int cin = r/CCH, cout = r%CCH;
    int o = (t*CCH + cout)*CCH + cin;
    w1[o] = (_Float16)k1[tid]; w2[o] = (_Float16)k2[tid]; return;
  }
  tid -= 27*CCH*CCH;
  if (tid < CCH) {                         // zero sentinel rows (empty-voxel gather)
    valsh[NSLOTCAP*CCH + tid] = (_Float16)0.f;
    hh[NSLOTCAP*CCH + tid]    = (_Float16)0.f; return;
  }
  tid -= CCH;
  if (tid < (2*KEYS)/4) { ((int4*)cntslot)[tid] = make_int4(0,0,0,0); return; }
}
#define PREP0_THREADS (GVOX/4 + MAXTILES*4 + MAXTILES*4 + 27*CCH*CCH + CCH + (2*KEYS)/4)

// ---------------- prep1: (class, cell) key + packed coords + histogram -------
__global__ __launch_bounds__(256) void k_prep1(const int* __restrict__ idx,
                                               int* __restrict__ key,
                                               int* __restrict__ pk,
                                               int* __restrict__ cnt)
{
  const int n = blockIdx.x*256 + threadIdx.x;
  const int4 v = ((const int4*)idx)[n];
  const int b = v.x, z = v.y, y = v.z, x = v.w;
  pk[n] = (b<<18) | (z<<12) | (y<<6) | x;  // == linear voxel index for B=1..
  const int cz = (z==0)?0:((z==DDIM-1)?2:1);
  const int cy = (y==0)?0:((y==DDIM-1)?2:1);
  const int cx = (x==0)?0:((x==DDIM-1)?2:1);
  const int c = cz*9 + cy*3 + cx;
  const int cell = ((z>>3)<<6) | ((y>>3)<<3) | (x>>3);
  const int k = (c<<9) | cell;
  key[n] = k;
  atomicAdd(&cnt[k], 1);
}

// ---------------- k_scan: exclusive scan over 13824 keys, padded per class ---
__global__ __launch_bounds__(256) void k_scan(const int* __restrict__ cnt,
                                              int* __restrict__ keybase,
                                              int* __restrict__ tstart,
                                              int* __restrict__ ntiles)
{
  __shared__ int E[KEYS];                  // 54 KB
  __shared__ int ts[256];
  __shared__ int clsb[27], clsu[27];
  const int t = threadIdx.x;
  int run = 0;
  for (int i = 0; i < CHUNK; ++i) {
    const int k = t*CHUNK + i;
    const int v = cnt[k];
    E[k] = run; run += v;
  }
  ts[t] = run;
  __syncthreads();
  if (t == 0) {
    int r = 0;
    for (int i = 0; i < 256; ++i) { const int v = ts[i]; ts[i] = r; r += v; }
  }
  __syncthreads();
  const int off = ts[t];
  for (int i = 0; i < CHUNK; ++i) E[t*CHUNK + i] += off;
  __syncthreads();
  if (t == 0) {
    int b = 0, tb = 0;
    for (int c = 0; c < 27; ++c) {
      const int start = E[c*NCELL];
      const int end   = (c == 26) ? NPTS : E[(c+1)*NCELL];
      clsu[c] = start; clsb[c] = b; tstart[c] = tb;
      const int ntc = (end - start + 15) >> 4;
      b += ntc << 4; tb += ntc;
    }
    tstart[27] = tb; *ntiles = tb;
  }
  __syncthreads();
  for (int i = 0; i < CHUNK; ++i) {
    const int k = t*CHUNK + i, c = k >> 9;
    keybase[k] = clsb[c] + (E[k] - clsu[c]);
  }
}

// ---------------- prep3: scatter to rank order; map stores SLOT; convert A ---
__global__ __launch_bounds__(256) void k_prep3(const int* __restrict__ key,
                                               const int* __restrict__ pk,
                                               const float* __restrict__ values,
                                               const int* __restrict__ keybase,
                                               int* __restrict__ slot,
                                               int* __restrict__ sorted,
                                               int* __restrict__ map,
                                               int* __restrict__ pcoords,
                                               _Float16* __restrict__ valsh,
                                               const int* __restrict__ tstart,
                                               int* __restrict__ tileclass,
                                               const int* __restrict__ ntp)
{
  if (blockIdx.x < NPTS/256) {
    const int n = blockIdx.x*256 + threadIdx.x;
    const int k = key[n], p = pk[n];
    const int s = keybase[k] + atomicAdd(&slot[k], 1);
    sorted[s] = n;
    pcoords[s] = p;
    map[p] = s;
    const float4* src = (const float4*)(values + n*CCH);
    half8* dst = (half8*)(valsh + s*CCH);
#pragma unroll
    for (int i = 0; i < 4; ++i) {
      float4 a = src[2*i], b = src[2*i+1];
      half8 h = {(_Float16)a.x,(_Float16)a.y,(_Float16)a.z,(_Float16)a.w,
                 (_Float16)b.x,(_Float16)b.y,(_Float16)b.z,(_Float16)b.w};
      dst[i] = h;
    }
  } else {
    const int i = (blockIdx.x - NPTS/256)*256 + threadIdx.x;
    if (i >= MAXTILES) return;
    const int nt = *ntp;
    int c = 13;
    if (i < nt) {
      for (int cc = 0; cc < 27; ++cc)
        if (i >= tstart[cc] && i < tstart[cc+1]) { c = cc; break; }
    }
    tileclass[i] = c;
  }
}

// ---------------- unified gather-MFMA conv, tap-split across 2 waves ---------
// A table is SLOT-indexed (sorted rank): map[voxel] = slot, empty = -1 -> zero
// row NSLOTCAP. Points in a tile share one 8^3 cell, so map/A gathers stay in
// a small L1-resident window across all 27 taps.
template<int J0, int J1>
__device__ __forceinline__ void accum_taps(
    const _Float16* __restrict__ A, const int* __restrict__ map,
    const _Float16* __restrict__ WT,
    int cz, int cy, int cx, int linb,
    const int* az, const int* ay, const int* ax,
    int m, int quad, floatx4& acc0, floatx4& acc1)
{
  int srcs[J1 - J0];
#pragma unroll
  for (int j = J0; j < J1; ++j) {
    const int jz = j/9, jy = (j/3)%3, jx = j%3;
    const int s = map[linb | az[jz] | ay[jy] | ax[jx]];
    srcs[j - J0] = (s < 0) ? (NSLOTCAP*CCH) : (s*CCH);
  }
#pragma unroll
  for (int j = J0; j < J1; ++j) {
    const int jz = j/9, jy = (j/3)%3, jx = j%3;
    const int tz = (cz==1) ? (2-jz) : ((jz==1) ? 1 : ((cz==0) ? 0 : 2));
    const int ty = (cy==1) ? (2-jy) : ((jy==1) ? 1 : ((cy==0) ? 0 : 2));
    const int tx = (cx==1) ? (2-jx) : ((jx==1) ? 1 : ((cx==0) ? 0 : 2));
    const int t  = tz*9 + ty*3 + tx;
    half8 a  = *(const half8*)(A + srcs[j - J0] + quad*8);
    const _Float16* wr = WT + t*(CCH*CCH);
    half8 b0 = *(const half8*)(wr + m*CCH + quad*8);
    half8 b1 = *(const half8*)(wr + (16+m)*CCH + quad*8);
    acc0 = __builtin_amdgcn_mfma_f32_16x16x32_f16(a, b0, acc0, 0, 0, 0);
    acc1 = __builtin_amdgcn_mfma_f32_16x16x32_f16(a, b1, acc1, 0, 0, 0);
  }
}

template<int MODE>
__global__ __launch_bounds__(256) void conv_mfma(
    const _Float16* __restrict__ A,        // (NSLOTCAP+1) x 32 f16, row NSLOTCAP = zeros
    const int* __restrict__ map,
    const int* __restrict__ pcoords,       // slot-indexed packed coords
    const int* __restrict__ sorted,        // slot -> original pid
    const int* __restrict__ tileclass,
    const int* __restrict__ ntp,
    const _Float16* __restrict__ WT,       // 27 x cout x cin f16
    const float* __restrict__ bias,
    const float* __restrict__ mask,
    const float* __restrict__ resid,
    _Float16* __restrict__ hout,           // slot-indexed
    float* __restrict__ fout)              // pid-indexed
{
  __shared__ float red[2][16][33];
  const int wv   = threadIdx.x >> 6;
  const int tl   = wv >> 1;
  const int half = wv & 1;
  const int tile = blockIdx.x*2 + tl;
  const int nt   = *ntp;
  const bool active = tile < nt;
  const int lane = threadIdx.x & 63;
  const int m = lane & 15, quad = lane >> 4;

  floatx4 acc0 = {0.f,0.f,0.f,0.f};
  floatx4 acc1 = {0.f,0.f,0.f,0.f};

  if (active) {
    const int scls = __builtin_amdgcn_readfirstlane(tileclass[tile]);
    const int cz = scls/9, cy = (scls/3)%3, cx = scls%3;
    const int pc = pcoords[tile*16 + m];
    const int bb = pc>>18, z = (pc>>12)&63, y = (pc>>6)&63, x = pc&63;
    const int linb = bb << 18;
    const int az[3] = { max(z-1,0)<<12, z<<12, min(z+1,DDIM-1)<<12 };
    const int ay[3] = { max(y-1,0)<<6,  y<<6,  min(y+1,DDIM-1)<<6 };
    const int ax[3] = { max(x-1,0),     x,     min(x+1,DDIM-1) };
    if (half == 0)
      accum_taps<0,14>(A, map, WT, cz,cy,cx, linb, az,ay,ax, m,quad, acc0,acc1);
    else
      accum_taps<14,27>(A, map, WT, cz,cy,cx, linb, az,ay,ax, m,quad, acc0,acc1);
  }

  if (active && half == 0) {
#pragma unroll
    for (int r = 0; r < 4; ++r) {
      red[tl][quad*4+r][m]    = acc0[r];
      red[tl][quad*4+r][m+16] = acc1[r];
    }
  }
  __syncthreads();
  if (active && half == 1) {
#pragma unroll
    for (int r = 0; r < 4; ++r) {
      acc0[r] += red[tl][quad*4+r][m];
      acc1[r] += red[tl][quad*4+r][m+16];
    }
    const float bi0 = bias[m], bi1 = bias[m+16];
#pragma unroll
    for (int reg = 0; reg < 4; ++reg) {
      const int r    = quad*4 + reg;
      const int srow = tile*16 + r;
      const int pr   = sorted[srow];
      if (pr >= NPTS) continue;            // padded slot
      const float mk = mask[pr];
      float v0 = (acc0[reg] + mk*bi0) * mk;
      float v1 = (acc1[reg] + mk*bi1) * mk;
      if (MODE == 0) {
        v0 = fmaxf(v0, 0.f); v1 = fmaxf(v1, 0.f);
        hout[srow*CCH + m]      = (_Float16)v0;   // contiguous per tile
        hout[srow*CCH + m + 16] = (_Float16)v1;
      } else {
        fout[pr*CCH + m]      = resid[pr*CCH + m]      + v0;
        fout[pr*CCH + m + 16] = resid[pr*CCH + m + 16] + v1;
      }
    }
  }
}

// ---------------- launch ----------------

extern "C" void kernel_launch(void* const* d_in, const int* in_sizes, int n_in,
                              void* d_out, int out_size, void* d_ws, size_t ws_size,
                              hipStream_t stream) {
  const float* values = (const float*)d_in[0];
  const int*   indices= (const int*)  d_in[1];
  const float* maskv  = (const float*)d_in[2];
  const float* kern1  = (const float*)d_in[3];
  const float* bias1  = (const float*)d_in[4];
  const float* kern2  = (const float*)d_in[5];
  const float* bias2  = (const float*)d_in[6];
  float* out = (float*)d_out;

  char* ws = (char*)d_ws;
  size_t off = 0;
  auto alloc = [&](size_t bytes) { void* p = ws + off; off = (off + bytes + 255) & ~(size_t)255; return p; };
  int*      map      = (int*)     alloc(GVOX*4);                   // 1 MB
  int*      key      = (int*)     alloc(NPTS*4);
  int*      pk       = (int*)     alloc(NPTS*4);
  int*      sorted   = (int*)     alloc(NSLOTCAP*4);
  int*      pcoords  = (int*)     alloc(NSLOTCAP*4);
  int*      tileclass= (int*)     alloc(MAXTILES*4);
  int*      cntslot  = (int*)     alloc(2*KEYS*4);                 // cnt | slot
  int*      keybase  = (int*)     alloc(KEYS*4);
  int*      tstart   = (int*)     alloc(28*4);
  int*      ntiles   = (int*)     alloc(4);
  _Float16* valsh    = (_Float16*)alloc((size_t)(NSLOTCAP+1)*CCH*2);  // ~4.2 MB
  _Float16* hh       = (_Float16*)alloc((size_t)(NSLOTCAP+1)*CCH*2);  // ~4.2 MB
  _Float16* wt1      = (_Float16*)alloc(27*CCH*CCH*2);
  _Float16* wt2      = (_Float16*)alloc(27*CCH*CCH*2);
  int* cnt  = cntslot;
  int* slot = cntslot + KEYS;

  k_prep0<<<(PREP0_THREADS + 255)/256, 256, 0, stream>>>(
      map, sorted, pcoords, kern1, kern2, wt1, wt2, valsh, hh, cntslot);
  k_prep1<<<NPTS/256, 256, 0, stream>>>(indices, key, pk, cnt);
  k_scan<<<1, 256, 0, stream>>>(cnt, keybase, tstart, ntiles);
  k_prep3<<<NPTS/256 + (MAXTILES+255)/256, 256, 0, stream>>>(
      key, pk, values, keybase, slot, sorted, map, pcoords, valsh,
      tstart, tileclass, ntiles);

  conv_mfma<0><<<MAXTILES/2, 256, 0, stream>>>(valsh, map, pcoords, sorted, tileclass,
                                               ntiles, wt1, bias1, maskv, nullptr, hh, nullptr);
  conv_mfma<1><<<MAXTILES/2, 256, 0, stream>>>(hh, map, pcoords, sorted, tileclass,
                                               ntiles, wt2, bias2, maskv, values, nullptr, out);
}